// Round 17
// baseline (189.890 us; speedup 1.0000x reference)
//
#include <hip/hip_runtime.h>
#include <cstdint>
#include <cstddef>

typedef unsigned short u16;
typedef __bf16 bf16x8 __attribute__((ext_vector_type(8)));
typedef float f32x4 __attribute__((ext_vector_type(4)));
typedef u16 u16x4 __attribute__((ext_vector_type(4)));

#define DMODEL 1024
#define DINNER 2048
#define NBATCH 2
#define LSEQ   2048
#define NTOK   4096   // NBATCH * LSEQ
#define NSTATE 16
#define NCH    64     // scan chunks
#define TCH    32     // timesteps per chunk (NCH*TCH == LSEQ)

__device__ __forceinline__ u16 f2b(float f) {
  union { float f; unsigned u; } a; a.f = f;
  unsigned r = a.u + 0x7fffu + ((a.u >> 16) & 1u);
  return (u16)(r >> 16);
}
__device__ __forceinline__ float b2f(u16 h) {
  union { unsigned u; float f; } a; a.u = ((unsigned)h) << 16;
  return a.f;
}

__device__ __forceinline__ void gload_lds16(const u16* g, __bf16* l) {
  __builtin_amdgcn_global_load_lds(
      (const __attribute__((address_space(1))) unsigned int*)g,
      (__attribute__((address_space(3))) unsigned int*)l, 16, 0, 0);
}

// p[s] = w^(s+1), depth-4 multiply tree (15 muls)
__device__ __forceinline__ void pow16(float w, float* p) {
  p[0] = w;
  p[1] = p[0] * p[0];
  p[2] = p[1] * p[0];
  p[3] = p[1] * p[1];
  p[4] = p[3] * p[0];
  p[5] = p[3] * p[1];
  p[6] = p[3] * p[2];
  p[7] = p[3] * p[3];
  p[8]  = p[7] * p[0];
  p[9]  = p[7] * p[1];
  p[10] = p[7] * p[2];
  p[11] = p[7] * p[3];
  p[12] = p[7] * p[4];
  p[13] = p[7] * p[5];
  p[14] = p[7] * p[6];
  p[15] = p[7] * p[7];
}

// ================== ONE-SHOT PREP: all transposes + bias + RMSNorm ==================
__global__ __launch_bounds__(256)
void prep_all(const float* __restrict__ w_in, const float* __restrict__ w_out,
              const float* __restrict__ w_dti, const float* __restrict__ w_b,
              const float* __restrict__ w_c, const float* __restrict__ w_dto,
              const float* __restrict__ b_dto, const float* __restrict__ dtbias,
              const float* __restrict__ x, const float* __restrict__ nscale,
              u16* __restrict__ WINT, u16* __restrict__ WOUTT, u16* __restrict__ WBC,
              u16* __restrict__ WDT2T, float* __restrict__ DTB2, u16* __restrict__ XN) {
  __shared__ float sh[32 * 33];
  const int tid = threadIdx.x;
  const int xx = tid & 31, y0 = tid >> 5;
  int blk = blockIdx.x;
  if (blk < 4096) {                       // w_in transpose
    int c0 = (blk & 127) * 32, r0 = (blk >> 7) * 32;
    #pragma unroll
    for (int yy = y0; yy < 32; yy += 8) sh[yy * 33 + xx] = w_in[(size_t)(r0 + yy) * 4096 + c0 + xx];
    __syncthreads();
    #pragma unroll
    for (int yy = y0; yy < 32; yy += 8) WINT[(size_t)(c0 + yy) * 1024 + r0 + xx] = f2b(sh[xx * 33 + yy]);
    return;
  }
  blk -= 4096;
  if (blk < 2048) {                       // w_out transpose
    int c0 = (blk & 31) * 32, r0 = (blk >> 5) * 32;
    #pragma unroll
    for (int yy = y0; yy < 32; yy += 8) sh[yy * 33 + xx] = w_out[(size_t)(r0 + yy) * 1024 + c0 + xx];
    __syncthreads();
    #pragma unroll
    for (int yy = y0; yy < 32; yy += 8) WOUTT[(size_t)(c0 + yy) * 2048 + r0 + xx] = f2b(sh[xx * 33 + yy]);
    return;
  }
  blk -= 2048;
  if (blk < 192) {                        // combined dti|b|c transpose
    int c0 = (blk % 3) * 32, r0 = (blk / 3) * 32;
    #pragma unroll
    for (int yy = y0; yy < 32; yy += 8) {
      int r = r0 + yy, c = c0 + xx;
      float v = (c < 64) ? w_dti[(size_t)r * 64 + c]
                         : (c < 80 ? w_b[(size_t)r * 16 + (c - 64)] : w_c[(size_t)r * 16 + (c - 80)]);
      sh[yy * 33 + xx] = v;
    }
    __syncthreads();
    #pragma unroll
    for (int yy = y0; yy < 32; yy += 8) WBC[(size_t)(c0 + yy) * 2048 + r0 + xx] = f2b(sh[xx * 33 + yy]);
    return;
  }
  blk -= 192;
  if (blk < 128) {                        // w_dto transpose
    int c0 = (blk & 63) * 32, r0 = (blk >> 6) * 32;
    #pragma unroll
    for (int yy = y0; yy < 32; yy += 8) sh[yy * 33 + xx] = w_dto[(size_t)(r0 + yy) * 2048 + c0 + xx];
    __syncthreads();
    #pragma unroll
    for (int yy = y0; yy < 32; yy += 8) WDT2T[(size_t)(c0 + yy) * 64 + r0 + xx] = f2b(sh[xx * 33 + yy]);
    return;
  }
  blk -= 128;
  if (blk < 8) {                          // bias combine
    int i = blk * 256 + tid;
    DTB2[i] = b_dto[i] + dtbias[i];
    return;
  }
  blk -= 8;
  {                                       // RMSNorm row
    const float4* xp = (const float4*)(x + (size_t)blk * DMODEL);
    float4 v = xp[tid];
    float ss = v.x * v.x + v.y * v.y + v.z * v.z + v.w * v.w;
    #pragma unroll
    for (int o = 32; o; o >>= 1) ss += __shfl_down(ss, o);
    if ((tid & 63) == 0) sh[tid >> 6] = ss;
    __syncthreads();
    float tot = sh[0] + sh[1] + sh[2] + sh[3];
    float r = rsqrtf(tot * (1.0f / DMODEL) + 1e-6f);
    float4 sc = ((const float4*)nscale)[tid];
    u16x4 o4;
    o4[0] = f2b(v.x * r * sc.x); o4[1] = f2b(v.y * r * sc.y);
    o4[2] = f2b(v.z * r * sc.z); o4[3] = f2b(v.w * r * sc.w);
    *(u16x4*)(XN + (size_t)blk * DMODEL + tid * 4) = o4;
  }
}

// ======== 256x256 8-PHASE GEMM: reg-carried B frags (24 ds_read/tile), 5 barriers ========
__global__ __launch_bounds__(512, 1)
void gemm8p(const u16* __restrict__ A, const u16* __restrict__ Bt,
            const float* __restrict__ bias, u16* __restrict__ out,
            int M, int N, int K, int RM, int RN) {
  __shared__ __bf16 lds[65536];   // [buf:2][mat:2][half:2][8192]; epilogue reuses as [128][264]
  const int tid = threadIdx.x;
  const int lane = tid & 63;
  const int wave = tid >> 6;
  const int wr = wave >> 2, wc = wave & 3;

  const int GM = M >> 8;
  const int bid = blockIdx.x;
  const int xcd = bid & 7;
  const int l = bid >> 3;
  const int rgm = GM / RM;
  const int rr = xcd % rgm, rc = xcd / rgm;
  const size_t m0 = (size_t)(rr * RM + (l % RM)) * 256;
  const size_t n0 = (size_t)(rc * RN + (l / RM)) * 256;
  const int NT = K >> 6;

  const int st_kk = ((tid & 7) * 8) ^ (((tid >> 3) & 7) << 3);

#define SHALF(bufi, mat, half, kt, SRC, BASE)                                  \
  { _Pragma("unroll") for (int ss = 0; ss < 2; ss++) {                         \
      const int row_ = (tid >> 3) + ss * 64;                                   \
      gload_lds16(SRC + ((BASE) + (half) * 128 + row_) * K + (size_t)(kt) * 64 + st_kk, \
                  &lds[((bufi) * 2 + (mat)) * 16384 + (half) * 8192 + tid * 8 + ss * 4096]); } }

  f32x4 acc[8][4] = {};
  SHALF(0, 0, 0, 0, A,  m0)  SHALF(0, 1, 0, 0, Bt, n0)
  SHALF(0, 0, 1, 0, A,  m0)  SHALF(0, 1, 1, 0, Bt, n0)
  if (NT > 1) { SHALF(1, 0, 0, 1, A, m0)  SHALF(1, 1, 0, 1, Bt, n0) }

  const int rsw = (lane & 7) << 3;
  const int kgrp = (lane >> 4) * 8;
  const int arl = wr * 64 + (lane & 15);
  const int brl = wc * 32 + (lane & 15);

  bf16x8 af[2][4], bv0[2][2], bv1[2][2];

#define DSA(QR)                                                                \
  { _Pragma("unroll") for (int ks = 0; ks < 2; ks++)                           \
      _Pragma("unroll") for (int i = 0; i < 4; i++)                            \
        af[ks][i] = *(const bf16x8*)(&lds[cur * 32768 + (QR) * 8192 +          \
                      (arl + i * 16) * 64 + ((ks * 32 + kgrp) ^ rsw)]); }
#define DSB(QC, BV)                                                            \
  { _Pragma("unroll") for (int ks = 0; ks < 2; ks++)                           \
      _Pragma("unroll") for (int j = 0; j < 2; j++)                            \
        BV[ks][j] = *(const bf16x8*)(&lds[cur * 32768 + 16384 + (QC) * 8192 +  \
                      (brl + j * 16) * 64 + ((ks * 32 + kgrp) ^ rsw)]); }
#define MMA_CORE(QR, QC, BV)                                                   \
  __builtin_amdgcn_s_barrier();                                                \
  asm volatile("s_waitcnt lgkmcnt(0)" ::: "memory");                           \
  __builtin_amdgcn_sched_barrier(0);                                           \
  __builtin_amdgcn_s_setprio(1);                                               \
  { _Pragma("unroll") for (int ks = 0; ks < 2; ks++)                           \
      _Pragma("unroll") for (int i = 0; i < 4; i++)                            \
        _Pragma("unroll") for (int j = 0; j < 2; j++)                          \
          acc[(QR) * 4 + i][(QC) * 2 + j] = __builtin_amdgcn_mfma_f32_16x16x32_bf16( \
              af[ks][i], BV[ks][j], acc[(QR) * 4 + i][(QC) * 2 + j], 0, 0, 0); } \
  __builtin_amdgcn_s_setprio(0);                                               \
  __builtin_amdgcn_sched_barrier(0);

  for (int t = 0; t < NT; t++) {
    const int cur = t & 1;
    if (t == NT - 1) asm volatile("s_waitcnt vmcnt(0)" ::: "memory");
    else             asm volatile("s_waitcnt vmcnt(8)" ::: "memory");
    __builtin_amdgcn_s_barrier();
    asm volatile("" ::: "memory");
    DSA(0) DSB(0, bv0)
    if (t + 1 < NT) { SHALF(cur ^ 1, 0, 1, t + 1, A, m0) }
    MMA_CORE(0, 0, bv0)
    if (t < NT - 1) asm volatile("s_waitcnt vmcnt(6)" ::: "memory");
    DSB(1, bv1)
    if (t + 1 < NT) { SHALF(cur ^ 1, 1, 1, t + 1, Bt, n0) }
    MMA_CORE(0, 1, bv1)
    DSA(1)
    if (t + 2 < NT) { SHALF(cur, 0, 0, t + 2, A, m0) }
    MMA_CORE(1, 0, bv0)
    if (t + 2 < NT) { SHALF(cur, 1, 0, t + 2, Bt, n0) }
    MMA_CORE(1, 1, bv1)
  }

  // epilogue: stage through LDS [128][264] u16 -> coalesced bf16x8 stores
  u16* eps = (u16*)lds;
  const int cr = (lane >> 4) << 2;
  const int cc = lane & 15;
  #pragma unroll
  for (int g = 0; g < 2; g++) {
    __syncthreads();
    #pragma unroll
    for (int fr4 = 0; fr4 < 4; fr4++) {
      const int lrow = wr * 64 + fr4 * 16 + cr;
      #pragma unroll
      for (int fc = 0; fc < 4; fc++) {
        const int lcol = wc * 32 + (fc >> 1) * 128 + (fc & 1) * 16 + cc;
        const float bvs = bias[n0 + lcol];
        #pragma unroll
        for (int r = 0; r < 4; r++)
          eps[(lrow + r) * 264 + lcol] = f2b(acc[g * 4 + fr4][fc][r] + bvs);
      }
    }
    __syncthreads();
    #pragma unroll
    for (int p = 0; p < 8; p++) {
      const int row = (tid >> 5) + p * 16;
      const int col = (tid & 31) * 8;
      bf16x8 v = *(const bf16x8*)&eps[row * 264 + col];
      *(bf16x8*)&out[(m0 + g * 128 + row) * N + n0 + col] = v;
    }
  }
#undef SHALF
#undef DSA
#undef DSB
#undef MMA_CORE
}

// ======== double-buffered counted-vmcnt MFMA GEMM with XCD-rect L2 blocking ========
// EPI: 0 = +bias -> bf16, 3 = +bias+residual -> f32 (LDS-staged coalesced epilogue)
template <int BM, int BN, int NWM, int NWN, int EPI>
__global__ __launch_bounds__(NWM * NWN * 64, 1)
void gemm_db(const u16* __restrict__ A, const u16* __restrict__ Bt,
             const float* __restrict__ bias, const float* __restrict__ res,
             void* __restrict__ outv, int M, int N, int K, int RM, int RN) {
  constexpr int NTHR = NWM * NWN * 64;
  constexpr int WMW = BM / NWM;
  constexpr int WNW = BN / NWN;
  constexpr int MF = WMW / 16;
  constexpr int NF = WNW / 16;
  constexpr int LPT = (BM + BN) * 8 / NTHR;
  __shared__ __bf16 lds[2][(BM + BN) * 64];
  const int tid = threadIdx.x;
  const int lane = tid & 63;
  const int wave = tid >> 6;
  const int wr = wave / NWN, wc = wave % NWN;

  const int GM = M / BM;
  const int bid = blockIdx.x;
  const int xcd = bid & 7;
  const int l = bid >> 3;
  const int rgm = GM / RM;
  const int rr = xcd % rgm, rc = xcd / rgm;
  const size_t m0 = (size_t)(rr * RM + (l % RM)) * BM;
  const size_t n0 = (size_t)(rc * RN + (l / RM)) * BN;
  const int NT = K >> 6;

#define STAGE_DB(bufi, k0)                                                     \
  { _Pragma("unroll")                                                          \
    for (int ss = 0; ss < BM * 8 / NTHR; ss++) {                               \
      int g = tid + ss * NTHR;                                                 \
      int row = g >> 3;                                                        \
      int kk = ((g & 7) * 8) ^ ((row & 7) << 3);                               \
      gload_lds16(A + (m0 + row) * K + (k0) + kk, &lds[bufi][g * 8]);          \
    }                                                                          \
    _Pragma("unroll")                                                          \
    for (int ss = 0; ss < BN * 8 / NTHR; ss++) {                               \
      int g = tid + ss * NTHR;                                                 \
      int row = g >> 3;                                                        \
      int kk = ((g & 7) * 8) ^ ((row & 7) << 3);                               \
      gload_lds16(Bt + (n0 + row) * K + (k0) + kk,                             \
                  &lds[bufi][BM * 64 + g * 8]);                                \
    } }

  f32x4 acc[MF][NF] = {};
  STAGE_DB(0, 0)
  STAGE_DB(1, 64)

  const int rsw = (lane & 7) << 3;
  const int arow0 = wr * WMW + (lane & 15);
  const int brow0 = wc * WNW + (lane & 15);
  const int kgrp = (lane >> 4) * 8;

  for (int t = 0; t < NT; t++) {
    const int cur = t & 1;
    if (t == NT - 1) asm volatile("s_waitcnt vmcnt(0)" ::: "memory");
    else             asm volatile("s_waitcnt vmcnt(%0)" :: "n"(LPT) : "memory");
    __builtin_amdgcn_s_barrier();
    asm volatile("" ::: "memory");
    const __bf16* As_ = &lds[cur][0];
    const __bf16* Bs_ = &lds[cur][BM * 64];
    #pragma unroll
    for (int qr = 0; qr < MF / 4; qr++) {
      #pragma unroll
      for (int qc = 0; qc < NF / 2; qc++) {
        bf16x8 af[2][4], bfv[2][2];
        #pragma unroll
        for (int ks = 0; ks < 2; ks++) {
          const int kk = (ks * 32 + kgrp) ^ rsw;
          #pragma unroll
          for (int i = 0; i < 4; i++)
            af[ks][i] = *(const bf16x8*)(As_ + (size_t)(arow0 + (qr * 4 + i) * 16) * 64 + kk);
          #pragma unroll
          for (int j = 0; j < 2; j++)
            bfv[ks][j] = *(const bf16x8*)(Bs_ + (size_t)(brow0 + (qc * 2 + j) * 16) * 64 + kk);
        }
        __builtin_amdgcn_s_setprio(1);
        #pragma unroll
        for (int ks = 0; ks < 2; ks++)
          #pragma unroll
          for (int i = 0; i < 4; i++)
            #pragma unroll
            for (int j = 0; j < 2; j++)
              acc[qr * 4 + i][qc * 2 + j] = __builtin_amdgcn_mfma_f32_16x16x32_bf16(
                  af[ks][i], bfv[ks][j], acc[qr * 4 + i][qc * 2 + j], 0, 0, 0);
        __builtin_amdgcn_s_setprio(0);
        __builtin_amdgcn_sched_barrier(0);
      }
    }
    __builtin_amdgcn_s_barrier();
    asm volatile("" ::: "memory");
    if (t + 2 < NT) { STAGE_DB(cur, (t + 2) * 64) }
  }

  const int cr = (lane >> 4) << 2;
  const int cc = lane & 15;
  if constexpr (EPI == 3) {
    float* flds = (float*)lds;
    __syncthreads();
    #pragma unroll
    for (int fr = 0; fr < MF; fr++) {
      #pragma unroll
      for (int fc = 0; fc < NF; fc++) {
        const int col = wc * WNW + fc * 16 + cc;
        const float bv = bias[n0 + col];
        #pragma unroll
        for (int r = 0; r < 4; r++)
          flds[(wr * WMW + fr * 16 + cr + r) * 68 + col] = acc[fr][fc][r] + bv;
      }
    }
    __syncthreads();
    constexpr int ROWS_PER_PASS = NTHR * 4 / BN;
    #pragma unroll
    for (int p = 0; p < BM / ROWS_PER_PASS; p++) {
      const int row = (tid / (BN / 4)) + p * ROWS_PER_PASS;
      const int c4 = (tid % (BN / 4)) * 4;
      float4 v = *(const float4*)&flds[row * 68 + c4];
      const float4 rs = *(const float4*)&res[(m0 + row) * N + n0 + c4];
      v.x += rs.x; v.y += rs.y; v.z += rs.z; v.w += rs.w;
      *(float4*)&((float*)outv)[(m0 + row) * N + n0 + c4] = v;
    }
  } else {
    #pragma unroll
    for (int fr = 0; fr < MF; fr++) {
      #pragma unroll
      for (int fc = 0; fc < NF; fc++) {
        const size_t col = n0 + wc * WNW + fc * 16 + cc;
        const float bv = bias[col];
        #pragma unroll
        for (int r = 0; r < 4; r++) {
          const size_t row = m0 + wr * WMW + fr * 16 + cr + r;
          ((u16*)outv)[row * N + col] = f2b(acc[fr][fc][r] + bv);
        }
      }
    }
  }
#undef STAGE_DB
}

// ---------------- padded reg-staged 2-phase GEMM for small shapes (BM templated)
// EPI: 1 = plain -> f32 partial (blockIdx.z offset), 2 = softplus+clip(+bias) -> bf16
template <int EPI, int BM, int BN>
__global__ __launch_bounds__(256)
void gemm_bt(const u16* __restrict__ A, const u16* __restrict__ Bt,
             const float* __restrict__ bias, const float* __restrict__ res,
             void* __restrict__ outv, int M, int N, int K, int ksplit) {
  constexpr int WN = BN / 2;
  constexpr int JN = WN / 16;
  constexpr int WM = BM / 2;
  constexpr int MI = WM / 16;
  __shared__ __bf16 As[BM][72];
  __shared__ __bf16 Bs[BN][72];
  const int tid = threadIdx.x;
  const int m0 = blockIdx.y * BM;
  const int n0 = blockIdx.x * BN;
  const int wave = tid >> 6, lane = tid & 63;
  const int wm = (wave >> 1) * WM, wn = (wave & 1) * WN;
  const int sr = tid >> 3;
  const int sc = (tid & 7) * 8;
  const int kbeg = blockIdx.z * ksplit, kend = kbeg + ksplit;
  f32x4 acc[MI][JN] = {};
  for (int k0 = kbeg; k0 < kend; k0 += 64) {
    __syncthreads();
    #pragma unroll
    for (int r = 0; r < BM; r += 32)
      *(bf16x8*)&As[sr + r][sc] = *(const bf16x8*)(A + (size_t)(m0 + sr + r) * K + k0 + sc);
    #pragma unroll
    for (int r = 0; r < BN; r += 32)
      *(bf16x8*)&Bs[sr + r][sc] = *(const bf16x8*)(Bt + (size_t)(n0 + sr + r) * K + k0 + sc);
    __syncthreads();
    #pragma unroll
    for (int ks = 0; ks < 64; ks += 32) {
      const int kr = ks + ((lane >> 4) << 3);
      bf16x8 af[MI], bfr[JN];
      #pragma unroll
      for (int i = 0; i < MI; i++) af[i]  = *(const bf16x8*)&As[wm + (lane & 15) + i * 16][kr];
      #pragma unroll
      for (int j = 0; j < JN; j++) bfr[j] = *(const bf16x8*)&Bs[wn + (lane & 15) + j * 16][kr];
      #pragma unroll
      for (int i = 0; i < MI; i++)
        #pragma unroll
        for (int j = 0; j < JN; j++)
          acc[i][j] = __builtin_amdgcn_mfma_f32_16x16x32_bf16(af[i], bfr[j], acc[i][j], 0, 0, 0);
    }
  }
  const int cr = (lane >> 4) << 2;
  const int cc = lane & 15;
  #pragma unroll
  for (int i = 0; i < MI; i++) {
    #pragma unroll
    for (int j = 0; j < JN; j++) {
      const int col = n0 + wn + j * 16 + cc;
      #pragma unroll
      for (int r = 0; r < 4; r++) {
        const int row = m0 + wm + i * 16 + cr + r;
        float v = acc[i][j][r];
        if constexpr (EPI == 1) {
          ((float*)outv)[(size_t)blockIdx.z * M * N + (size_t)row * N + col] = v;
        } else {
          v += bias[col];
          v = (v > 20.0f) ? v : log1pf(__expf(v));
          v = fminf(fmaxf(v, 0.001f), 0.1f);
          ((u16*)outv)[(size_t)row * N + col] = f2b(v);
        }
      }
    }
  }
}

// ---------------- causal depthwise conv(4) + bias + SiLU -> bf16 (16-step chunks)
__global__ __launch_bounds__(256)
void conv_silu_seq(const u16* __restrict__ uz, const float* __restrict__ ck,
                   const float* __restrict__ cb, u16* __restrict__ u) {
  int d  = (blockIdx.x & 7) * 256 + threadIdx.x;
  int lc = (blockIdx.x >> 3) & 127;
  int b  = blockIdx.x >> 10;
  const float w0 = ck[d], w1 = ck[DINNER + d], w2 = ck[2 * DINNER + d], w3 = ck[3 * DINNER + d];
  const float bias = cb[d];
  const int t0 = lc * 16;
  float x0 = 0.f, x1 = 0.f, x2 = 0.f;
  #pragma unroll
  for (int j = -3; j < 0; j++) {
    int t = t0 + j;
    float v = (t >= 0) ? b2f(uz[((size_t)(b * LSEQ + t)) * (2 * DINNER) + d]) : 0.f;
    x0 = x1; x1 = x2; x2 = v;
  }
  #pragma unroll
  for (int i = 0; i < 16; i++) {
    int t = t0 + i;
    float x3 = b2f(uz[((size_t)(b * LSEQ + t)) * (2 * DINNER) + d]);
    float acc = bias + w0 * x0 + w1 * x1 + w2 * x2 + w3 * x3;
    float sv = acc / (1.0f + __expf(-acc));
    u[((size_t)(b * LSEQ + t)) * DINNER + d] = f2b(sv);
    x0 = x1; x1 = x2; x2 = x3;
  }
}

// ---------------- reduce split-K partials + split dtbc (N=96)
__global__ __launch_bounds__(256)
void prep_dtbc(const float* __restrict__ dtbc, const float* __restrict__ dtin_b,
               const float* __restrict__ bb, const float* __restrict__ cbias,
               u16* __restrict__ dt1, float* __restrict__ Bm, float* __restrict__ Cm) {
  int idx = blockIdx.x * 256 + threadIdx.x;
  if (idx >= NTOK * 96) return;
  int row = idx / 96, col = idx - row * 96;
  float v = 0.f;
  #pragma unroll
  for (int z = 0; z < 8; z++)
    v += dtbc[(size_t)z * NTOK * 96 + (size_t)row * 96 + col];
  if (col < 64)       dt1[(size_t)row * 64 + col] = f2b(v + dtin_b[col]);
  else if (col < 80)  Bm[(size_t)row * NSTATE + col - 64] = tanhf(v + bb[col - 64]);
  else                Cm[(size_t)row * NSTATE + col - 80] = tanhf(v + cbias[col - 80]);
}

// ======== chunked selective scan: 1 thread per d, 16 states, NCH=64 chunks ========
// Structured-A fast path (guarded, generic fallback). chS/hst carried as bf16.
__global__ __launch_bounds__(256)
void scan_pass1(const u16* __restrict__ dt, const u16* __restrict__ u,
                const float* __restrict__ Bm, const float* __restrict__ alog,
                float* __restrict__ chP, u16* __restrict__ chS) {
  const int d  = (blockIdx.x & 7) * 256 + threadIdx.x;
  const int ch = (blockIdx.x >> 3) & (NCH - 1);
  const int b  = blockIdx.x >> 9;
  float A[NSTATE];
  #pragma unroll
  for (int s = 0; s < NSTATE; s++) A[s] = -__expf(alog[(size_t)d * NSTATE + s]);
  const float A0 = A[0];
  bool structured = true;
  #pragma unroll
  for (int s = 1; s < NSTATE; s++)
    structured = structured && (fabsf(A[s] - (s + 1) * A0) <= 1e-4f * fabsf((s + 1) * A0));
  float h[NSTATE];
  #pragma unroll
  for (int s = 0; s < NSTATE; s++) h[s] = 0.0f;
  const int t0 = ch * TCH;
  size_t base = (((size_t)b * NCH + ch) * DINNER + d) * NSTATE;
  if (structured) {
    float sdt = 0.f;
    for (int i = 0; i < TCH; i++) {
      const size_t tok = (size_t)b * LSEQ + t0 + i;
      float dtv = b2f(dt[tok * DINNER + d]);
      float uv  = b2f(u[tok * DINNER + d]);
      float dtu = dtv * uv;
      const float* bp = Bm + tok * NSTATE;
      sdt += dtv;
      float p[NSTATE];
      pow16(__expf(dtv * A0), p);
      #pragma unroll
      for (int s = 0; s < NSTATE; s++) h[s] = p[s] * h[s] + dtu * bp[s];
    }
    float P[NSTATE];
    pow16(__expf(sdt * A0), P);
    #pragma unroll
    for (int s = 0; s < NSTATE; s++) { chP[base + s] = P[s]; chS[base + s] = f2b(h[s]); }
  } else {
    float P[NSTATE];
    #pragma unroll
    for (int s = 0; s < NSTATE; s++) P[s] = 1.0f;
    for (int i = 0; i < TCH; i++) {
      const size_t tok = (size_t)b * LSEQ + t0 + i;
      float dtv = b2f(dt[tok * DINNER + d]);
      float uv  = b2f(u[tok * DINNER + d]);
      float dtu = dtv * uv;
      const float* bp = Bm + tok * NSTATE;
      #pragma unroll
      for (int s = 0; s < NSTATE; s++) {
        float da = __expf(dtv * A[s]);
        P[s] *= da;
        h[s] = da * h[s] + dtu * bp[s];
      }
    }
    #pragma unroll
    for (int s = 0; s < NSTATE; s++) { chP[base + s] = P[s]; chS[base + s] = f2b(h[s]); }
  }
}

// pass2: stitch chunks; hst MAY alias chS (read-before-write, same index)
__global__ __launch_bounds__(256)
void scan_pass2(const float* __restrict__ chP, const u16* __restrict__ chS,
                u16* __restrict__ hst) {
  const int b   = blockIdx.x >> 7;
  const int off = (blockIdx.x & 127) * 256 + threadIdx.x;
  float h = 0.f;
  const size_t stride = (size_t)DINNER * NSTATE;
  size_t base = (size_t)b * NCH * stride + off;
  for (int c = 0; c < NCH; c++) {
    size_t a = base + (size_t)c * stride;
    float P = chP[a];
    float S = b2f(chS[a]);
    hst[a] = f2b(h);
    h = P * h + S;
  }
}

// pass3: replay + y = (sum h*c + u*d) * silu(z) -> bf16 (structured-A fast path)
__global__ __launch_bounds__(256)
void scan_pass3(const u16* __restrict__ dt, const u16* __restrict__ u,
                const float* __restrict__ Bm, const float* __restrict__ Cm,
                const float* __restrict__ alog, const float* __restrict__ dvec,
                const u16* __restrict__ uz, const u16* __restrict__ hst,
                u16* __restrict__ y) {
  const int d  = (blockIdx.x & 7) * 256 + threadIdx.x;
  const int ch = (blockIdx.x >> 3) & (NCH - 1);
  const int b  = blockIdx.x >> 9;
  float A[NSTATE];
  #pragma unroll
  for (int s = 0; s < NSTATE; s++) A[s] = -__expf(alog[(size_t)d * NSTATE + s]);
  const float A0 = A[0];
  bool structured = true;
  #pragma unroll
  for (int s = 1; s < NSTATE; s++)
    structured = structured && (fabsf(A[s] - (s + 1) * A0) <= 1e-4f * fabsf((s + 1) * A0));
  float h[NSTATE];
  const size_t hbase = (((size_t)b * NCH + ch) * DINNER + d) * NSTATE;
  #pragma unroll
  for (int s = 0; s < NSTATE; s++) h[s] = b2f(hst[hbase + s]);
  const float dval = dvec[d];
  const int t0 = ch * TCH;
  if (structured) {
    for (int i = 0; i < TCH; i++) {
      const size_t tok = (size_t)b * LSEQ + t0 + i;
      float dtv = b2f(dt[tok * DINNER + d]);
      float uv  = b2f(u[tok * DINNER + d]);
      float dtu = dtv * uv;
      const float* bp = Bm + tok * NSTATE;
      const float* cp = Cm + tok * NSTATE;
      float p[NSTATE];
      pow16(__expf(dtv * A0), p);
      float yv = 0.0f;
      #pragma unroll
      for (int s = 0; s < NSTATE; s++) {
        h[s] = p[s] * h[s] + dtu * bp[s];
        yv += h[s] * cp[s];
      }
      yv += uv * dval;
      float z = b2f(uz[tok * (2 * DINNER) + DINNER + d]);
      float g = z / (1.0f + __expf(-z));
      y[tok * DINNER + d] = f2b(yv * g);
    }
  } else {
    for (int i = 0; i < TCH; i++) {
      const size_t tok = (size_t)b * LSEQ + t0 + i;
      float dtv = b2f(dt[tok * DINNER + d]);
      float uv  = b2f(u[tok * DINNER + d]);
      float dtu = dtv * uv;
      const float* bp = Bm + tok * NSTATE;
      const float* cp = Cm + tok * NSTATE;
      float yv = 0.0f;
      #pragma unroll
      for (int s = 0; s < NSTATE; s++) {
        float da = __expf(dtv * A[s]);
        h[s] = da * h[s] + dtu * bp[s];
        yv += h[s] * cp[s];
      }
      yv += uv * dval;
      float z = b2f(uz[tok * (2 * DINNER) + DINNER + d]);
      float g = z / (1.0f + __expf(-z));
      y[tok * DINNER + d] = f2b(yv * g);
    }
  }
}

// ---------------- workspace layout (bytes) — with aliases
#define WS_XN     ((size_t)0)                  // 8388608
#define WS_WINT   (WS_XN     + 8388608)        // 8388608
#define WS_CHP    ((size_t)0)                  // 16777216 (alias over XN+WINT)
#define WS_WOUTT  (WS_WINT   + 8388608)        // 4194304
#define WS_WBC    (WS_WOUTT  + 4194304)        // 393216 (slot 524288)
#define WS_WDT2T  (WS_WBC    + 524288)         // 262144
#define WS_DT1    (WS_WDT2T  + 262144)         // 524288
#define WS_DTB2   (WS_DT1    + 524288)         // 8192
#define WS_BMAT   (WS_DTB2   + 8192)           // 262144
#define WS_CMAT   (WS_BMAT   + 262144)         // 262144
#define WS_UZ     (WS_CMAT   + 262144)         // 33554432
#define WS_U      (WS_UZ     + 33554432)       // 16777216
#define WS_DTBC   (WS_U      + 16777216)       // 12582912 (slot 16777216)
#define WS_DT     (WS_DTBC   + 16777216)       // 16777216
#define WS_CHS    (WS_DT     + 16777216)       // u16 8388608 (== HST; slot 16777216)
#define WS_YBF    (WS_CHS    + 16777216)       // 16777216

extern "C" void kernel_launch(void* const* d_in, const int* in_sizes, int n_in,
                              void* d_out, int out_size, void* d_ws, size_t ws_size,
                              hipStream_t stream) {
  const float* x      = (const float*)d_in[0];
  const float* nscale = (const float*)d_in[1];
  const float* w_in   = (const float*)d_in[2];
  const float* b_in   = (const float*)d_in[3];
  const float* w_out  = (const float*)d_in[4];
  const float* b_out  = (const float*)d_in[5];
  const float* w_dti  = (const float*)d_in[6];
  const float* b_dti  = (const float*)d_in[7];
  const float* w_dto  = (const float*)d_in[8];
  const float* b_dto  = (const float*)d_in[9];
  const float* w_b    = (const float*)d_in[10];
  const float* b_b    = (const float*)d_in[11];
  const float* w_c    = (const float*)d_in[12];
  const float* b_c    = (const float*)d_in[13];
  const float* convk  = (const float*)d_in[14];
  const float* convb  = (const float*)d_in[15];
  const float* alog   = (const float*)d_in[16];
  const float* dvec   = (const float*)d_in[17];
  const float* dtbias = (const float*)d_in[18];
  float* out = (float*)d_out;
  char* ws = (char*)d_ws;

  u16*  XN    = (u16*)(ws + WS_XN);
  u16*  WINT  = (u16*)(ws + WS_WINT);
  u16*  WOUTT = (u16*)(ws + WS_WOUTT);
  u16*  WBC   = (u16*)(ws + WS_WBC);
  u16*  WDT2T = (u16*)(ws + WS_WDT2T);
  u16*  DT1   = (u16*)(ws + WS_DT1);
  float* DTB2 = (float*)(ws + WS_DTB2);
  float* BMAT = (float*)(ws + WS_BMAT);
  float* CMAT = (float*)(ws + WS_CMAT);
  u16*  UZ    = (u16*)(ws + WS_UZ);
  u16*  U     = (u16*)(ws + WS_U);
  float* DTBC = (float*)(ws + WS_DTBC);
  u16*  DT    = (u16*)(ws + WS_DT);
  float* CHP  = (float*)(ws + WS_CHP);
  u16*  CHS   = (u16*)(ws + WS_CHS);
  u16*  HST   = (u16*)(ws + WS_CHS);    // alias: pass2 reads chS then writes hst
  u16*  YBF   = (u16*)(ws + WS_YBF);

  // all weight prep + RMSNorm in ONE launch
  prep_all<<<10568, 256, 0, stream>>>(w_in, w_out, w_dti, w_b, w_c, w_dto,
                                      b_dto, dtbias, x, nscale,
                                      WINT, WOUTT, WBC, WDT2T, DTB2, XN);

  // in_proj: 8-phase 256^2, reg-carried B frags, grid 256, XCD rect 4x8
  gemm8p<<<256, 512, 0, stream>>>(XN, WINT, b_in, UZ, NTOK, 4096, 1024, 4, 8);

  // conv + silu (read-once, 16-step chunks)
  conv_silu_seq<<<NBATCH * 128 * 8, 256, 0, stream>>>(UZ, convk, convb, U);

  // dt1 / B / C: N=96, BM=64 -> grid (1,64,8)=512 blocks (2/CU), split-K=8
  gemm_bt<1, 64, 96><<<dim3(1, NTOK / 64, 8), 256, 0, stream>>>(
      U, WBC, nullptr, nullptr, DTBC, NTOK, 96, 2048, 256);
  prep_dtbc<<<(NTOK * 96 + 255) / 256, 256, 0, stream>>>(DTBC, b_dti, b_b, b_c, DT1, BMAT, CMAT);

  // dt2 + softplus + clip -> bf16 DT (BN=64 -> 1024 blocks)
  gemm_bt<2, 128, 64><<<dim3(2048 / 64, NTOK / 128, 1), 256, 0, stream>>>(
      DT1, WDT2T, DTB2, nullptr, DT, NTOK, 2048, 64, 64);

  // chunked selective scan (NCH=64 -> 1024 blocks/pass; bf16 chS/hst)
  scan_pass1<<<NBATCH * NCH * 8, 256, 0, stream>>>(DT, U, BMAT, alog, CHP, CHS);
  scan_pass2<<<NBATCH * 128, 256, 0, stream>>>(CHP, CHS, HST);
  scan_pass3<<<NBATCH * NCH * 8, 256, 0, stream>>>(DT, U, BMAT, CMAT, alog, dvec, UZ, HST, YBF);

  // out_proj + residual: 128x64 tiles, grid 512 = 2 blocks/CU, LDS-staged epilogue
  gemm_db<128, 64, 2, 2, 3><<<512, 256, 0, stream>>>(
      YBF, WOUTT, b_out, x, out, NTOK, 1024, 2048, 8, 8);
}

// Round 18
// 187.223 us; speedup vs baseline: 1.0142x; 1.0142x over previous
//
#include <hip/hip_runtime.h>
#include <cstdint>
#include <cstddef>

typedef unsigned short u16;
typedef __bf16 bf16x8 __attribute__((ext_vector_type(8)));
typedef float f32x4 __attribute__((ext_vector_type(4)));
typedef u16 u16x4 __attribute__((ext_vector_type(4)));

#define DMODEL 1024
#define DINNER 2048
#define NBATCH 2
#define LSEQ   2048
#define NTOK   4096   // NBATCH * LSEQ
#define NSTATE 16
#define NCH    64     // scan chunks
#define TCH    32     // timesteps per chunk (NCH*TCH == LSEQ)

__device__ __forceinline__ u16 f2b(float f) {
  union { float f; unsigned u; } a; a.f = f;
  unsigned r = a.u + 0x7fffu + ((a.u >> 16) & 1u);
  return (u16)(r >> 16);
}
__device__ __forceinline__ float b2f(u16 h) {
  union { unsigned u; float f; } a; a.u = ((unsigned)h) << 16;
  return a.f;
}

__device__ __forceinline__ void gload_lds16(const u16* g, __bf16* l) {
  __builtin_amdgcn_global_load_lds(
      (const __attribute__((address_space(1))) unsigned int*)g,
      (__attribute__((address_space(3))) unsigned int*)l, 16, 0, 0);
}

// p[s] = w^(s+1), depth-4 multiply tree (15 muls)
__device__ __forceinline__ void pow16(float w, float* p) {
  p[0] = w;
  p[1] = p[0] * p[0];
  p[2] = p[1] * p[0];
  p[3] = p[1] * p[1];
  p[4] = p[3] * p[0];
  p[5] = p[3] * p[1];
  p[6] = p[3] * p[2];
  p[7] = p[3] * p[3];
  p[8]  = p[7] * p[0];
  p[9]  = p[7] * p[1];
  p[10] = p[7] * p[2];
  p[11] = p[7] * p[3];
  p[12] = p[7] * p[4];
  p[13] = p[7] * p[5];
  p[14] = p[7] * p[6];
  p[15] = p[7] * p[7];
}

// ================== ONE-SHOT PREP: all transposes + bias + RMSNorm ==================
__global__ __launch_bounds__(256)
void prep_all(const float* __restrict__ w_in, const float* __restrict__ w_out,
              const float* __restrict__ w_dti, const float* __restrict__ w_b,
              const float* __restrict__ w_c, const float* __restrict__ w_dto,
              const float* __restrict__ b_dto, const float* __restrict__ dtbias,
              const float* __restrict__ x, const float* __restrict__ nscale,
              u16* __restrict__ WINT, u16* __restrict__ WOUTT, u16* __restrict__ WBC,
              u16* __restrict__ WDT2T, float* __restrict__ DTB2, u16* __restrict__ XN) {
  __shared__ float sh[32 * 33];
  const int tid = threadIdx.x;
  const int xx = tid & 31, y0 = tid >> 5;
  int blk = blockIdx.x;
  if (blk < 4096) {                       // w_in transpose
    int c0 = (blk & 127) * 32, r0 = (blk >> 7) * 32;
    #pragma unroll
    for (int yy = y0; yy < 32; yy += 8) sh[yy * 33 + xx] = w_in[(size_t)(r0 + yy) * 4096 + c0 + xx];
    __syncthreads();
    #pragma unroll
    for (int yy = y0; yy < 32; yy += 8) WINT[(size_t)(c0 + yy) * 1024 + r0 + xx] = f2b(sh[xx * 33 + yy]);
    return;
  }
  blk -= 4096;
  if (blk < 2048) {                       // w_out transpose
    int c0 = (blk & 31) * 32, r0 = (blk >> 5) * 32;
    #pragma unroll
    for (int yy = y0; yy < 32; yy += 8) sh[yy * 33 + xx] = w_out[(size_t)(r0 + yy) * 1024 + c0 + xx];
    __syncthreads();
    #pragma unroll
    for (int yy = y0; yy < 32; yy += 8) WOUTT[(size_t)(c0 + yy) * 2048 + r0 + xx] = f2b(sh[xx * 33 + yy]);
    return;
  }
  blk -= 2048;
  if (blk < 192) {                        // combined dti|b|c transpose
    int c0 = (blk % 3) * 32, r0 = (blk / 3) * 32;
    #pragma unroll
    for (int yy = y0; yy < 32; yy += 8) {
      int r = r0 + yy, c = c0 + xx;
      float v = (c < 64) ? w_dti[(size_t)r * 64 + c]
                         : (c < 80 ? w_b[(size_t)r * 16 + (c - 64)] : w_c[(size_t)r * 16 + (c - 80)]);
      sh[yy * 33 + xx] = v;
    }
    __syncthreads();
    #pragma unroll
    for (int yy = y0; yy < 32; yy += 8) WBC[(size_t)(c0 + yy) * 2048 + r0 + xx] = f2b(sh[xx * 33 + yy]);
    return;
  }
  blk -= 192;
  if (blk < 128) {                        // w_dto transpose
    int c0 = (blk & 63) * 32, r0 = (blk >> 6) * 32;
    #pragma unroll
    for (int yy = y0; yy < 32; yy += 8) sh[yy * 33 + xx] = w_dto[(size_t)(r0 + yy) * 2048 + c0 + xx];
    __syncthreads();
    #pragma unroll
    for (int yy = y0; yy < 32; yy += 8) WDT2T[(size_t)(c0 + yy) * 64 + r0 + xx] = f2b(sh[xx * 33 + yy]);
    return;
  }
  blk -= 128;
  if (blk < 8) {                          // bias combine
    int i = blk * 256 + tid;
    DTB2[i] = b_dto[i] + dtbias[i];
    return;
  }
  blk -= 8;
  {                                       // RMSNorm row
    const float4* xp = (const float4*)(x + (size_t)blk * DMODEL);
    float4 v = xp[tid];
    float ss = v.x * v.x + v.y * v.y + v.z * v.z + v.w * v.w;
    #pragma unroll
    for (int o = 32; o; o >>= 1) ss += __shfl_down(ss, o);
    if ((tid & 63) == 0) sh[tid >> 6] = ss;
    __syncthreads();
    float tot = sh[0] + sh[1] + sh[2] + sh[3];
    float r = rsqrtf(tot * (1.0f / DMODEL) + 1e-6f);
    float4 sc = ((const float4*)nscale)[tid];
    u16x4 o4;
    o4[0] = f2b(v.x * r * sc.x); o4[1] = f2b(v.y * r * sc.y);
    o4[2] = f2b(v.z * r * sc.z); o4[3] = f2b(v.w * r * sc.w);
    *(u16x4*)(XN + (size_t)blk * DMODEL + tid * 4) = o4;
  }
}

// ======== 256x256 8-PHASE GEMM: reg-carried B frags (24 ds_read/tile), 5 barriers ========
__global__ __launch_bounds__(512, 1)
void gemm8p(const u16* __restrict__ A, const u16* __restrict__ Bt,
            const float* __restrict__ bias, u16* __restrict__ out,
            int M, int N, int K, int RM, int RN) {
  __shared__ __bf16 lds[65536];   // [buf:2][mat:2][half:2][8192]; epilogue reuses as [128][264]
  const int tid = threadIdx.x;
  const int lane = tid & 63;
  const int wave = tid >> 6;
  const int wr = wave >> 2, wc = wave & 3;

  const int GM = M >> 8;
  const int bid = blockIdx.x;
  const int xcd = bid & 7;
  const int l = bid >> 3;
  const int rgm = GM / RM;
  const int rr = xcd % rgm, rc = xcd / rgm;
  const size_t m0 = (size_t)(rr * RM + (l % RM)) * 256;
  const size_t n0 = (size_t)(rc * RN + (l / RM)) * 256;
  const int NT = K >> 6;

  const int st_kk = ((tid & 7) * 8) ^ (((tid >> 3) & 7) << 3);

#define SHALF(bufi, mat, half, kt, SRC, BASE)                                  \
  { _Pragma("unroll") for (int ss = 0; ss < 2; ss++) {                         \
      const int row_ = (tid >> 3) + ss * 64;                                   \
      gload_lds16(SRC + ((BASE) + (half) * 128 + row_) * K + (size_t)(kt) * 64 + st_kk, \
                  &lds[((bufi) * 2 + (mat)) * 16384 + (half) * 8192 + tid * 8 + ss * 4096]); } }

  f32x4 acc[8][4] = {};
  SHALF(0, 0, 0, 0, A,  m0)  SHALF(0, 1, 0, 0, Bt, n0)
  SHALF(0, 0, 1, 0, A,  m0)  SHALF(0, 1, 1, 0, Bt, n0)
  if (NT > 1) { SHALF(1, 0, 0, 1, A, m0)  SHALF(1, 1, 0, 1, Bt, n0) }

  const int rsw = (lane & 7) << 3;
  const int kgrp = (lane >> 4) * 8;
  const int arl = wr * 64 + (lane & 15);
  const int brl = wc * 32 + (lane & 15);

  bf16x8 af[2][4], bv0[2][2], bv1[2][2];

#define DSA(QR)                                                                \
  { _Pragma("unroll") for (int ks = 0; ks < 2; ks++)                           \
      _Pragma("unroll") for (int i = 0; i < 4; i++)                            \
        af[ks][i] = *(const bf16x8*)(&lds[cur * 32768 + (QR) * 8192 +          \
                      (arl + i * 16) * 64 + ((ks * 32 + kgrp) ^ rsw)]); }
#define DSB(QC, BV)                                                            \
  { _Pragma("unroll") for (int ks = 0; ks < 2; ks++)                           \
      _Pragma("unroll") for (int j = 0; j < 2; j++)                            \
        BV[ks][j] = *(const bf16x8*)(&lds[cur * 32768 + 16384 + (QC) * 8192 +  \
                      (brl + j * 16) * 64 + ((ks * 32 + kgrp) ^ rsw)]); }
#define MMA_CORE(QR, QC, BV)                                                   \
  __builtin_amdgcn_s_barrier();                                                \
  asm volatile("s_waitcnt lgkmcnt(0)" ::: "memory");                           \
  __builtin_amdgcn_sched_barrier(0);                                           \
  __builtin_amdgcn_s_setprio(1);                                               \
  { _Pragma("unroll") for (int ks = 0; ks < 2; ks++)                           \
      _Pragma("unroll") for (int i = 0; i < 4; i++)                            \
        _Pragma("unroll") for (int j = 0; j < 2; j++)                          \
          acc[(QR) * 4 + i][(QC) * 2 + j] = __builtin_amdgcn_mfma_f32_16x16x32_bf16( \
              af[ks][i], BV[ks][j], acc[(QR) * 4 + i][(QC) * 2 + j], 0, 0, 0); } \
  __builtin_amdgcn_s_setprio(0);                                               \
  __builtin_amdgcn_sched_barrier(0);

  for (int t = 0; t < NT; t++) {
    const int cur = t & 1;
    if (t == NT - 1) asm volatile("s_waitcnt vmcnt(0)" ::: "memory");
    else             asm volatile("s_waitcnt vmcnt(8)" ::: "memory");
    __builtin_amdgcn_s_barrier();
    asm volatile("" ::: "memory");
    DSA(0) DSB(0, bv0)
    if (t + 1 < NT) { SHALF(cur ^ 1, 0, 1, t + 1, A, m0) }
    MMA_CORE(0, 0, bv0)
    if (t < NT - 1) asm volatile("s_waitcnt vmcnt(6)" ::: "memory");
    DSB(1, bv1)
    if (t + 1 < NT) { SHALF(cur ^ 1, 1, 1, t + 1, Bt, n0) }
    MMA_CORE(0, 1, bv1)
    DSA(1)
    if (t + 2 < NT) { SHALF(cur, 0, 0, t + 2, A, m0) }
    MMA_CORE(1, 0, bv0)
    if (t + 2 < NT) { SHALF(cur, 1, 0, t + 2, Bt, n0) }
    MMA_CORE(1, 1, bv1)
  }

  // epilogue: stage through LDS [128][264] u16 -> coalesced bf16x8 stores
  u16* eps = (u16*)lds;
  const int cr = (lane >> 4) << 2;
  const int cc = lane & 15;
  #pragma unroll
  for (int g = 0; g < 2; g++) {
    __syncthreads();
    #pragma unroll
    for (int fr4 = 0; fr4 < 4; fr4++) {
      const int lrow = wr * 64 + fr4 * 16 + cr;
      #pragma unroll
      for (int fc = 0; fc < 4; fc++) {
        const int lcol = wc * 32 + (fc >> 1) * 128 + (fc & 1) * 16 + cc;
        const float bvs = bias[n0 + lcol];
        #pragma unroll
        for (int r = 0; r < 4; r++)
          eps[(lrow + r) * 264 + lcol] = f2b(acc[g * 4 + fr4][fc][r] + bvs);
      }
    }
    __syncthreads();
    #pragma unroll
    for (int p = 0; p < 8; p++) {
      const int row = (tid >> 5) + p * 16;
      const int col = (tid & 31) * 8;
      bf16x8 v = *(const bf16x8*)&eps[row * 264 + col];
      *(bf16x8*)&out[(m0 + g * 128 + row) * N + n0 + col] = v;
    }
  }
#undef SHALF
#undef DSA
#undef DSB
#undef MMA_CORE
}

// ======== double-buffered counted-vmcnt MFMA GEMM with XCD-rect L2 blocking ========
// EPI: 0 = +bias -> bf16, 3 = +bias+residual -> f32 (LDS-staged coalesced epilogue)
template <int BM, int BN, int NWM, int NWN, int EPI>
__global__ __launch_bounds__(NWM * NWN * 64, 1)
void gemm_db(const u16* __restrict__ A, const u16* __restrict__ Bt,
             const float* __restrict__ bias, const float* __restrict__ res,
             void* __restrict__ outv, int M, int N, int K, int RM, int RN) {
  constexpr int NTHR = NWM * NWN * 64;
  constexpr int WMW = BM / NWM;
  constexpr int WNW = BN / NWN;
  constexpr int MF = WMW / 16;
  constexpr int NF = WNW / 16;
  constexpr int LPT = (BM + BN) * 8 / NTHR;
  __shared__ __bf16 lds[2][(BM + BN) * 64];
  const int tid = threadIdx.x;
  const int lane = tid & 63;
  const int wave = tid >> 6;
  const int wr = wave / NWN, wc = wave % NWN;

  const int GM = M / BM;
  const int bid = blockIdx.x;
  const int xcd = bid & 7;
  const int l = bid >> 3;
  const int rgm = GM / RM;
  const int rr = xcd % rgm, rc = xcd / rgm;
  const size_t m0 = (size_t)(rr * RM + (l % RM)) * BM;
  const size_t n0 = (size_t)(rc * RN + (l / RM)) * BN;
  const int NT = K >> 6;

#define STAGE_DB(bufi, k0)                                                     \
  { _Pragma("unroll")                                                          \
    for (int ss = 0; ss < BM * 8 / NTHR; ss++) {                               \
      int g = tid + ss * NTHR;                                                 \
      int row = g >> 3;                                                        \
      int kk = ((g & 7) * 8) ^ ((row & 7) << 3);                               \
      gload_lds16(A + (m0 + row) * K + (k0) + kk, &lds[bufi][g * 8]);          \
    }                                                                          \
    _Pragma("unroll")                                                          \
    for (int ss = 0; ss < BN * 8 / NTHR; ss++) {                               \
      int g = tid + ss * NTHR;                                                 \
      int row = g >> 3;                                                        \
      int kk = ((g & 7) * 8) ^ ((row & 7) << 3);                               \
      gload_lds16(Bt + (n0 + row) * K + (k0) + kk,                             \
                  &lds[bufi][BM * 64 + g * 8]);                                \
    } }

  f32x4 acc[MF][NF] = {};
  STAGE_DB(0, 0)
  STAGE_DB(1, 64)

  const int rsw = (lane & 7) << 3;
  const int arow0 = wr * WMW + (lane & 15);
  const int brow0 = wc * WNW + (lane & 15);
  const int kgrp = (lane >> 4) * 8;

  for (int t = 0; t < NT; t++) {
    const int cur = t & 1;
    if (t == NT - 1) asm volatile("s_waitcnt vmcnt(0)" ::: "memory");
    else             asm volatile("s_waitcnt vmcnt(%0)" :: "n"(LPT) : "memory");
    __builtin_amdgcn_s_barrier();
    asm volatile("" ::: "memory");
    const __bf16* As_ = &lds[cur][0];
    const __bf16* Bs_ = &lds[cur][BM * 64];
    #pragma unroll
    for (int qr = 0; qr < MF / 4; qr++) {
      #pragma unroll
      for (int qc = 0; qc < NF / 2; qc++) {
        bf16x8 af[2][4], bfv[2][2];
        #pragma unroll
        for (int ks = 0; ks < 2; ks++) {
          const int kk = (ks * 32 + kgrp) ^ rsw;
          #pragma unroll
          for (int i = 0; i < 4; i++)
            af[ks][i] = *(const bf16x8*)(As_ + (size_t)(arow0 + (qr * 4 + i) * 16) * 64 + kk);
          #pragma unroll
          for (int j = 0; j < 2; j++)
            bfv[ks][j] = *(const bf16x8*)(Bs_ + (size_t)(brow0 + (qc * 2 + j) * 16) * 64 + kk);
        }
        __builtin_amdgcn_s_setprio(1);
        #pragma unroll
        for (int ks = 0; ks < 2; ks++)
          #pragma unroll
          for (int i = 0; i < 4; i++)
            #pragma unroll
            for (int j = 0; j < 2; j++)
              acc[qr * 4 + i][qc * 2 + j] = __builtin_amdgcn_mfma_f32_16x16x32_bf16(
                  af[ks][i], bfv[ks][j], acc[qr * 4 + i][qc * 2 + j], 0, 0, 0);
        __builtin_amdgcn_s_setprio(0);
        __builtin_amdgcn_sched_barrier(0);
      }
    }
    __builtin_amdgcn_s_barrier();
    asm volatile("" ::: "memory");
    if (t + 2 < NT) { STAGE_DB(cur, (t + 2) * 64) }
  }

  const int cr = (lane >> 4) << 2;
  const int cc = lane & 15;
  if constexpr (EPI == 3) {
    float* flds = (float*)lds;
    __syncthreads();
    #pragma unroll
    for (int fr = 0; fr < MF; fr++) {
      #pragma unroll
      for (int fc = 0; fc < NF; fc++) {
        const int col = wc * WNW + fc * 16 + cc;
        const float bv = bias[n0 + col];
        #pragma unroll
        for (int r = 0; r < 4; r++)
          flds[(wr * WMW + fr * 16 + cr + r) * 68 + col] = acc[fr][fc][r] + bv;
      }
    }
    __syncthreads();
    constexpr int ROWS_PER_PASS = NTHR * 4 / BN;
    #pragma unroll
    for (int p = 0; p < BM / ROWS_PER_PASS; p++) {
      const int row = (tid / (BN / 4)) + p * ROWS_PER_PASS;
      const int c4 = (tid % (BN / 4)) * 4;
      float4 v = *(const float4*)&flds[row * 68 + c4];
      const float4 rs = *(const float4*)&res[(m0 + row) * N + n0 + c4];
      v.x += rs.x; v.y += rs.y; v.z += rs.z; v.w += rs.w;
      *(float4*)&((float*)outv)[(m0 + row) * N + n0 + c4] = v;
    }
  } else {
    #pragma unroll
    for (int fr = 0; fr < MF; fr++) {
      #pragma unroll
      for (int fc = 0; fc < NF; fc++) {
        const size_t col = n0 + wc * WNW + fc * 16 + cc;
        const float bv = bias[col];
        #pragma unroll
        for (int r = 0; r < 4; r++) {
          const size_t row = m0 + wr * WMW + fr * 16 + cr + r;
          ((u16*)outv)[row * N + col] = f2b(acc[fr][fc][r] + bv);
        }
      }
    }
  }
#undef STAGE_DB
}

// ---------------- padded reg-staged 2-phase GEMM for small shapes (BM templated)
// EPI: 1 = plain -> f32 partial (blockIdx.z offset), 2 = softplus+clip(+bias) -> bf16
template <int EPI, int BM, int BN>
__global__ __launch_bounds__(256)
void gemm_bt(const u16* __restrict__ A, const u16* __restrict__ Bt,
             const float* __restrict__ bias, const float* __restrict__ res,
             void* __restrict__ outv, int M, int N, int K, int ksplit) {
  constexpr int WN = BN / 2;
  constexpr int JN = WN / 16;
  constexpr int WM = BM / 2;
  constexpr int MI = WM / 16;
  __shared__ __bf16 As[BM][72];
  __shared__ __bf16 Bs[BN][72];
  const int tid = threadIdx.x;
  const int m0 = blockIdx.y * BM;
  const int n0 = blockIdx.x * BN;
  const int wave = tid >> 6, lane = tid & 63;
  const int wm = (wave >> 1) * WM, wn = (wave & 1) * WN;
  const int sr = tid >> 3;
  const int sc = (tid & 7) * 8;
  const int kbeg = blockIdx.z * ksplit, kend = kbeg + ksplit;
  f32x4 acc[MI][JN] = {};
  for (int k0 = kbeg; k0 < kend; k0 += 64) {
    __syncthreads();
    #pragma unroll
    for (int r = 0; r < BM; r += 32)
      *(bf16x8*)&As[sr + r][sc] = *(const bf16x8*)(A + (size_t)(m0 + sr + r) * K + k0 + sc);
    #pragma unroll
    for (int r = 0; r < BN; r += 32)
      *(bf16x8*)&Bs[sr + r][sc] = *(const bf16x8*)(Bt + (size_t)(n0 + sr + r) * K + k0 + sc);
    __syncthreads();
    #pragma unroll
    for (int ks = 0; ks < 64; ks += 32) {
      const int kr = ks + ((lane >> 4) << 3);
      bf16x8 af[MI], bfr[JN];
      #pragma unroll
      for (int i = 0; i < MI; i++) af[i]  = *(const bf16x8*)&As[wm + (lane & 15) + i * 16][kr];
      #pragma unroll
      for (int j = 0; j < JN; j++) bfr[j] = *(const bf16x8*)&Bs[wn + (lane & 15) + j * 16][kr];
      #pragma unroll
      for (int i = 0; i < MI; i++)
        #pragma unroll
        for (int j = 0; j < JN; j++)
          acc[i][j] = __builtin_amdgcn_mfma_f32_16x16x32_bf16(af[i], bfr[j], acc[i][j], 0, 0, 0);
    }
  }
  const int cr = (lane >> 4) << 2;
  const int cc = lane & 15;
  #pragma unroll
  for (int i = 0; i < MI; i++) {
    #pragma unroll
    for (int j = 0; j < JN; j++) {
      const int col = n0 + wn + j * 16 + cc;
      #pragma unroll
      for (int r = 0; r < 4; r++) {
        const int row = m0 + wm + i * 16 + cr + r;
        float v = acc[i][j][r];
        if constexpr (EPI == 1) {
          ((float*)outv)[(size_t)blockIdx.z * M * N + (size_t)row * N + col] = v;
        } else {
          v += bias[col];
          v = (v > 20.0f) ? v : log1pf(__expf(v));
          v = fminf(fmaxf(v, 0.001f), 0.1f);
          ((u16*)outv)[(size_t)row * N + col] = f2b(v);
        }
      }
    }
  }
}

// ---------------- causal depthwise conv(4) + bias + SiLU -> bf16 (16-step chunks)
__global__ __launch_bounds__(256)
void conv_silu_seq(const u16* __restrict__ uz, const float* __restrict__ ck,
                   const float* __restrict__ cb, u16* __restrict__ u) {
  int d  = (blockIdx.x & 7) * 256 + threadIdx.x;
  int lc = (blockIdx.x >> 3) & 127;
  int b  = blockIdx.x >> 10;
  const float w0 = ck[d], w1 = ck[DINNER + d], w2 = ck[2 * DINNER + d], w3 = ck[3 * DINNER + d];
  const float bias = cb[d];
  const int t0 = lc * 16;
  float x0 = 0.f, x1 = 0.f, x2 = 0.f;
  #pragma unroll
  for (int j = -3; j < 0; j++) {
    int t = t0 + j;
    float v = (t >= 0) ? b2f(uz[((size_t)(b * LSEQ + t)) * (2 * DINNER) + d]) : 0.f;
    x0 = x1; x1 = x2; x2 = v;
  }
  #pragma unroll
  for (int i = 0; i < 16; i++) {
    int t = t0 + i;
    float x3 = b2f(uz[((size_t)(b * LSEQ + t)) * (2 * DINNER) + d]);
    float acc = bias + w0 * x0 + w1 * x1 + w2 * x2 + w3 * x3;
    float sv = acc / (1.0f + __expf(-acc));
    u[((size_t)(b * LSEQ + t)) * DINNER + d] = f2b(sv);
    x0 = x1; x1 = x2; x2 = x3;
  }
}

// ---------------- reduce split-K partials + split dtbc (N=96)
__global__ __launch_bounds__(256)
void prep_dtbc(const float* __restrict__ dtbc, const float* __restrict__ dtin_b,
               const float* __restrict__ bb, const float* __restrict__ cbias,
               u16* __restrict__ dt1, float* __restrict__ Bm, float* __restrict__ Cm) {
  int idx = blockIdx.x * 256 + threadIdx.x;
  if (idx >= NTOK * 96) return;
  int row = idx / 96, col = idx - row * 96;
  float v = 0.f;
  #pragma unroll
  for (int z = 0; z < 8; z++)
    v += dtbc[(size_t)z * NTOK * 96 + (size_t)row * 96 + col];
  if (col < 64)       dt1[(size_t)row * 64 + col] = f2b(v + dtin_b[col]);
  else if (col < 80)  Bm[(size_t)row * NSTATE + col - 64] = tanhf(v + bb[col - 64]);
  else                Cm[(size_t)row * NSTATE + col - 80] = tanhf(v + cbias[col - 80]);
}

// ======== chunked selective scan: 1 thread per d, 16 states, NCH=64 chunks ========
// Structured-A fast path (guarded, generic fallback). chS/hst carried as bf16.
__global__ __launch_bounds__(256)
void scan_pass1(const u16* __restrict__ dt, const u16* __restrict__ u,
                const float* __restrict__ Bm, const float* __restrict__ alog,
                float* __restrict__ chP, u16* __restrict__ chS) {
  const int d  = (blockIdx.x & 7) * 256 + threadIdx.x;
  const int ch = (blockIdx.x >> 3) & (NCH - 1);
  const int b  = blockIdx.x >> 9;
  float A[NSTATE];
  #pragma unroll
  for (int s = 0; s < NSTATE; s++) A[s] = -__expf(alog[(size_t)d * NSTATE + s]);
  const float A0 = A[0];
  bool structured = true;
  #pragma unroll
  for (int s = 1; s < NSTATE; s++)
    structured = structured && (fabsf(A[s] - (s + 1) * A0) <= 1e-4f * fabsf((s + 1) * A0));
  float h[NSTATE];
  #pragma unroll
  for (int s = 0; s < NSTATE; s++) h[s] = 0.0f;
  const int t0 = ch * TCH;
  size_t base = (((size_t)b * NCH + ch) * DINNER + d) * NSTATE;
  if (structured) {
    float sdt = 0.f;
    for (int i = 0; i < TCH; i++) {
      const size_t tok = (size_t)b * LSEQ + t0 + i;
      float dtv = b2f(dt[tok * DINNER + d]);
      float uv  = b2f(u[tok * DINNER + d]);
      float dtu = dtv * uv;
      const float* bp = Bm + tok * NSTATE;
      sdt += dtv;
      float p[NSTATE];
      pow16(__expf(dtv * A0), p);
      #pragma unroll
      for (int s = 0; s < NSTATE; s++) h[s] = p[s] * h[s] + dtu * bp[s];
    }
    float P[NSTATE];
    pow16(__expf(sdt * A0), P);
    #pragma unroll
    for (int s = 0; s < NSTATE; s++) { chP[base + s] = P[s]; chS[base + s] = f2b(h[s]); }
  } else {
    float P[NSTATE];
    #pragma unroll
    for (int s = 0; s < NSTATE; s++) P[s] = 1.0f;
    for (int i = 0; i < TCH; i++) {
      const size_t tok = (size_t)b * LSEQ + t0 + i;
      float dtv = b2f(dt[tok * DINNER + d]);
      float uv  = b2f(u[tok * DINNER + d]);
      float dtu = dtv * uv;
      const float* bp = Bm + tok * NSTATE;
      #pragma unroll
      for (int s = 0; s < NSTATE; s++) {
        float da = __expf(dtv * A[s]);
        P[s] *= da;
        h[s] = da * h[s] + dtu * bp[s];
      }
    }
    #pragma unroll
    for (int s = 0; s < NSTATE; s++) { chP[base + s] = P[s]; chS[base + s] = f2b(h[s]); }
  }
}

// pass2: stitch chunks; hst MAY alias chS (read-before-write, same index)
__global__ __launch_bounds__(256)
void scan_pass2(const float* __restrict__ chP, const u16* __restrict__ chS,
                u16* __restrict__ hst) {
  const int b   = blockIdx.x >> 7;
  const int off = (blockIdx.x & 127) * 256 + threadIdx.x;
  float h = 0.f;
  const size_t stride = (size_t)DINNER * NSTATE;
  size_t base = (size_t)b * NCH * stride + off;
  for (int c = 0; c < NCH; c++) {
    size_t a = base + (size_t)c * stride;
    float P = chP[a];
    float S = b2f(chS[a]);
    hst[a] = f2b(h);
    h = P * h + S;
  }
}

// pass3: replay + y = (sum h*c + u*d) * silu(z) -> bf16 (structured-A fast path)
__global__ __launch_bounds__(256)
void scan_pass3(const u16* __restrict__ dt, const u16* __restrict__ u,
                const float* __restrict__ Bm, const float* __restrict__ Cm,
                const float* __restrict__ alog, const float* __restrict__ dvec,
                const u16* __restrict__ uz, const u16* __restrict__ hst,
                u16* __restrict__ y) {
  const int d  = (blockIdx.x & 7) * 256 + threadIdx.x;
  const int ch = (blockIdx.x >> 3) & (NCH - 1);
  const int b  = blockIdx.x >> 9;
  float A[NSTATE];
  #pragma unroll
  for (int s = 0; s < NSTATE; s++) A[s] = -__expf(alog[(size_t)d * NSTATE + s]);
  const float A0 = A[0];
  bool structured = true;
  #pragma unroll
  for (int s = 1; s < NSTATE; s++)
    structured = structured && (fabsf(A[s] - (s + 1) * A0) <= 1e-4f * fabsf((s + 1) * A0));
  float h[NSTATE];
  const size_t hbase = (((size_t)b * NCH + ch) * DINNER + d) * NSTATE;
  #pragma unroll
  for (int s = 0; s < NSTATE; s++) h[s] = b2f(hst[hbase + s]);
  const float dval = dvec[d];
  const int t0 = ch * TCH;
  if (structured) {
    for (int i = 0; i < TCH; i++) {
      const size_t tok = (size_t)b * LSEQ + t0 + i;
      float dtv = b2f(dt[tok * DINNER + d]);
      float uv  = b2f(u[tok * DINNER + d]);
      float dtu = dtv * uv;
      const float* bp = Bm + tok * NSTATE;
      const float* cp = Cm + tok * NSTATE;
      float p[NSTATE];
      pow16(__expf(dtv * A0), p);
      float yv = 0.0f;
      #pragma unroll
      for (int s = 0; s < NSTATE; s++) {
        h[s] = p[s] * h[s] + dtu * bp[s];
        yv += h[s] * cp[s];
      }
      yv += uv * dval;
      float z = b2f(uz[tok * (2 * DINNER) + DINNER + d]);
      float g = z / (1.0f + __expf(-z));
      y[tok * DINNER + d] = f2b(yv * g);
    }
  } else {
    for (int i = 0; i < TCH; i++) {
      const size_t tok = (size_t)b * LSEQ + t0 + i;
      float dtv = b2f(dt[tok * DINNER + d]);
      float uv  = b2f(u[tok * DINNER + d]);
      float dtu = dtv * uv;
      const float* bp = Bm + tok * NSTATE;
      const float* cp = Cm + tok * NSTATE;
      float yv = 0.0f;
      #pragma unroll
      for (int s = 0; s < NSTATE; s++) {
        float da = __expf(dtv * A[s]);
        h[s] = da * h[s] + dtu * bp[s];
        yv += h[s] * cp[s];
      }
      yv += uv * dval;
      float z = b2f(uz[tok * (2 * DINNER) + DINNER + d]);
      float g = z / (1.0f + __expf(-z));
      y[tok * DINNER + d] = f2b(yv * g);
    }
  }
}

// ---------------- workspace layout (bytes) — with aliases
#define WS_XN     ((size_t)0)                  // 8388608
#define WS_WINT   (WS_XN     + 8388608)        // 8388608
#define WS_CHP    ((size_t)0)                  // 16777216 (alias over XN+WINT)
#define WS_WOUTT  (WS_WINT   + 8388608)        // 4194304
#define WS_WBC    (WS_WOUTT  + 4194304)        // 393216 (slot 524288)
#define WS_WDT2T  (WS_WBC    + 524288)         // 262144
#define WS_DT1    (WS_WDT2T  + 262144)         // 524288
#define WS_DTB2   (WS_DT1    + 524288)         // 8192
#define WS_BMAT   (WS_DTB2   + 8192)           // 262144
#define WS_CMAT   (WS_BMAT   + 262144)         // 262144
#define WS_UZ     (WS_CMAT   + 262144)         // 33554432
#define WS_U      (WS_UZ     + 33554432)       // 16777216
#define WS_DTBC   (WS_U      + 16777216)       // 12582912 (slot 16777216)
#define WS_DT     (WS_DTBC   + 16777216)       // 16777216
#define WS_CHS    (WS_DT     + 16777216)       // u16 8388608 (== HST; slot 16777216)
#define WS_YBF    (WS_CHS    + 16777216)       // 16777216

extern "C" void kernel_launch(void* const* d_in, const int* in_sizes, int n_in,
                              void* d_out, int out_size, void* d_ws, size_t ws_size,
                              hipStream_t stream) {
  const float* x      = (const float*)d_in[0];
  const float* nscale = (const float*)d_in[1];
  const float* w_in   = (const float*)d_in[2];
  const float* b_in   = (const float*)d_in[3];
  const float* w_out  = (const float*)d_in[4];
  const float* b_out  = (const float*)d_in[5];
  const float* w_dti  = (const float*)d_in[6];
  const float* b_dti  = (const float*)d_in[7];
  const float* w_dto  = (const float*)d_in[8];
  const float* b_dto  = (const float*)d_in[9];
  const float* w_b    = (const float*)d_in[10];
  const float* b_b    = (const float*)d_in[11];
  const float* w_c    = (const float*)d_in[12];
  const float* b_c    = (const float*)d_in[13];
  const float* convk  = (const float*)d_in[14];
  const float* convb  = (const float*)d_in[15];
  const float* alog   = (const float*)d_in[16];
  const float* dvec   = (const float*)d_in[17];
  const float* dtbias = (const float*)d_in[18];
  float* out = (float*)d_out;
  char* ws = (char*)d_ws;

  u16*  XN    = (u16*)(ws + WS_XN);
  u16*  WINT  = (u16*)(ws + WS_WINT);
  u16*  WOUTT = (u16*)(ws + WS_WOUTT);
  u16*  WBC   = (u16*)(ws + WS_WBC);
  u16*  WDT2T = (u16*)(ws + WS_WDT2T);
  u16*  DT1   = (u16*)(ws + WS_DT1);
  float* DTB2 = (float*)(ws + WS_DTB2);
  float* BMAT = (float*)(ws + WS_BMAT);
  float* CMAT = (float*)(ws + WS_CMAT);
  u16*  UZ    = (u16*)(ws + WS_UZ);
  u16*  U     = (u16*)(ws + WS_U);
  float* DTBC = (float*)(ws + WS_DTBC);
  u16*  DT    = (u16*)(ws + WS_DT);
  float* CHP  = (float*)(ws + WS_CHP);
  u16*  CHS   = (u16*)(ws + WS_CHS);
  u16*  HST   = (u16*)(ws + WS_CHS);    // alias: pass2 reads chS then writes hst
  u16*  YBF   = (u16*)(ws + WS_YBF);

  // all weight prep + RMSNorm in ONE launch
  prep_all<<<10568, 256, 0, stream>>>(w_in, w_out, w_dti, w_b, w_c, w_dto,
                                      b_dto, dtbias, x, nscale,
                                      WINT, WOUTT, WBC, WDT2T, DTB2, XN);

  // in_proj: 8-phase 256^2, reg-carried B frags, grid 256, XCD rect 4x8
  gemm8p<<<256, 512, 0, stream>>>(XN, WINT, b_in, UZ, NTOK, 4096, 1024, 4, 8);

  // conv + silu (read-once, 16-step chunks)
  conv_silu_seq<<<NBATCH * 128 * 8, 256, 0, stream>>>(UZ, convk, convb, U);

  // dt1 / B / C: N=96, BM=128 (R16 proven), split-K=8
  gemm_bt<1, 128, 96><<<dim3(1, NTOK / 128, 8), 256, 0, stream>>>(
      U, WBC, nullptr, nullptr, DTBC, NTOK, 96, 2048, 256);
  prep_dtbc<<<(NTOK * 96 + 255) / 256, 256, 0, stream>>>(DTBC, b_dti, b_b, b_c, DT1, BMAT, CMAT);

  // dt2 + softplus + clip -> bf16 DT (BN=64 -> 1024 blocks)
  gemm_bt<2, 128, 64><<<dim3(2048 / 64, NTOK / 128, 1), 256, 0, stream>>>(
      DT1, WDT2T, DTB2, nullptr, DT, NTOK, 2048, 64, 64);

  // chunked selective scan (NCH=64 -> 1024 blocks/pass; bf16 chS/hst)
  scan_pass1<<<NBATCH * NCH * 8, 256, 0, stream>>>(DT, U, BMAT, alog, CHP, CHS);
  scan_pass2<<<NBATCH * 128, 256, 0, stream>>>(CHP, CHS, HST);
  scan_pass3<<<NBATCH * NCH * 8, 256, 0, stream>>>(DT, U, BMAT, CMAT, alog, dvec, UZ, HST, YBF);

  // out_proj + residual: 128x64 tiles, grid 512 = 2 blocks/CU, LDS-staged epilogue
  gemm_db<128, 64, 2, 2, 3><<<512, 256, 0, stream>>>(
      YBF, WOUTT, b_out, x, out, NTOK, 1024, 2048, 8, 8);
}